// Round 1
// baseline (246.985 us; speedup 1.0000x reference)
//
#include <hip/hip_runtime.h>
#include <hip/hip_bf16.h>
#include <cstdint>

typedef unsigned short u16;
typedef __bf16 bf16x8 __attribute__((ext_vector_type(8)));
typedef float f32x4 __attribute__((ext_vector_type(4)));

// ---------- helpers ----------
__device__ __forceinline__ u16 f2b(float f) {          // fp32 -> bf16 RNE
    unsigned int u = __float_as_uint(f);
    u += 0x7fffu + ((u >> 16) & 1u);
    return (u16)(u >> 16);
}
__device__ __forceinline__ float b2f(u16 h) {
    return __uint_as_float(((unsigned int)h) << 16);
}
__device__ __forceinline__ void async_cp16(void* lds, const void* g) {
    __builtin_amdgcn_global_load_lds((const __attribute__((address_space(1))) void*)g,
                                     (__attribute__((address_space(3))) void*)lds, 16, 0, 0);
}

// ---------- fp32 -> bf16 weight conversion ----------
__global__ __launch_bounds__(256) void cvt_bf16_kernel(const float* __restrict__ in,
                                                       u16* __restrict__ out, int n4) {
    int i = blockIdx.x * 256 + threadIdx.x;
    if (i < n4) {
        float4 v = *(const float4*)&in[(size_t)i * 4];
        ushort4 o;
        o.x = f2b(v.x); o.y = f2b(v.y); o.z = f2b(v.z); o.w = f2b(v.w);
        *(ushort4*)&out[(size_t)i * 4] = o;
    }
}

// ---------- [B][C][S] fp32 -> [B][S][C] bf16 transpose ----------
__global__ __launch_bounds__(256) void transpose_bf16_kernel(const float* __restrict__ in,
                                                             u16* __restrict__ out,
                                                             int C, int S) {
    __shared__ float t[64][65];
    int s0 = blockIdx.x * 64, c0 = blockIdx.y * 64, b = blockIdx.z;
    const float* ib = in + (size_t)b * C * S;
    u16* ob = out + (size_t)b * S * C;
    int col = threadIdx.x & 63, r0 = threadIdx.x >> 6;
#pragma unroll
    for (int p = 0; p < 16; ++p) {
        int c = p * 4 + r0;
        t[c][col] = ib[(size_t)(c0 + c) * S + s0 + col];
    }
    __syncthreads();
#pragma unroll
    for (int p = 0; p < 16; ++p) {
        int s = p * 4 + r0;
        ob[(size_t)(s0 + s) * C + c0 + col] = f2b(t[col][s]);
    }
}

// ---------- three_nn: top-3 NN + inverse-distance weights ----------
// block = 256 threads = 32 queries x 8 S-chunks; grid = 32768/32 = 1024
__global__ __launch_bounds__(256) void three_nn_kernel(const float* __restrict__ pos1,
                                                       const float* __restrict__ pos2,
                                                       int* __restrict__ idx_out,
                                                       float* __restrict__ w_out) {
    __shared__ float px[2048], py[2048], pz[2048], nn2[2048];
    __shared__ float md[256 * 3];
    __shared__ int   mi[256 * 3];
    int tid = threadIdx.x;
    int jl = tid & 31, ck = tid >> 5;
    int j = blockIdx.x * 32 + jl;
    int b = j >> 13, n = j & 8191;
    const float* p2 = pos2 + (size_t)b * 3 * 2048;
    for (int i = tid; i < 2048; i += 256) {
        float x = p2[i], y = p2[2048 + i], z = p2[4096 + i];
        px[i] = x; py[i] = y; pz[i] = z;
        nn2[i] = x * x + y * y + z * z;
    }
    __syncthreads();
    const float* p1 = pos1 + (size_t)b * 3 * 8192;
    float x1 = p1[n], y1 = p1[8192 + n], z1 = p1[16384 + n];
    float n1 = x1 * x1 + y1 * y1 + z1 * z1;
    float d0 = 3.4e38f, d1v = 3.4e38f, d2v = 3.4e38f;
    int i0 = 0, i1 = 0, i2 = 0;
    int sb = ck * 256;
    for (int s = sb; s < sb + 256; ++s) {
        float dot = x1 * px[s] + y1 * py[s] + z1 * pz[s];
        float d = n1 + nn2[s] - 2.f * dot;
        if (d < d2v) {
            if (d < d1v) {
                d2v = d1v; i2 = i1;
                if (d < d0) { d1v = d0; i1 = i0; d0 = d; i0 = s; }
                else        { d1v = d;  i1 = s; }
            } else { d2v = d; i2 = s; }
        }
    }
    int base = (jl * 8 + ck) * 3;
    md[base] = d0; md[base + 1] = d1v; md[base + 2] = d2v;
    mi[base] = i0; mi[base + 1] = i1;  mi[base + 2] = i2;
    __syncthreads();
    if (ck == 0) {
        float b0 = 3.4e38f, b1v = 3.4e38f, b2v = 3.4e38f;
        int q0 = 0, q1 = 0, q2 = 0;
        for (int c = 0; c < 8; ++c) {
            int bb = (jl * 8 + c) * 3;
            for (int r = 0; r < 3; ++r) {
                float d = md[bb + r]; int s = mi[bb + r];
                if (d < b2v) {
                    if (d < b1v) {
                        b2v = b1v; q2 = q1;
                        if (d < b0) { b1v = b0; q1 = q0; b0 = d; q0 = s; }
                        else        { b1v = d;  q1 = s; }
                    } else { b2v = d; q2 = s; }
                }
            }
        }
        float dd0 = fmaxf(b0, 1e-10f), dd1 = fmaxf(b1v, 1e-10f), dd2 = fmaxf(b2v, 1e-10f);
        float w0 = 1.f / dd0, w1 = 1.f / dd1, w2 = 1.f / dd2;
        float inv = 1.f / (w0 + w1 + w2);
        idx_out[j * 3] = q0; idx_out[j * 3 + 1] = q1; idx_out[j * 3 + 2] = q2;
        w_out[j * 3] = w0 * inv; w_out[j * 3 + 1] = w1 * inv; w_out[j * 3 + 2] = w2 * inv;
    }
}

// ---------- gather + interpolate + concat -> feat [32768][384] bf16 ----------
// one wave per query point; grid 8192 x 256 threads (4 waves)
__global__ __launch_bounds__(256) void gather_kernel(const u16* __restrict__ f2t,
                                                     const u16* __restrict__ f1t,
                                                     const int* __restrict__ idx,
                                                     const float* __restrict__ wgt,
                                                     u16* __restrict__ feat) {
    int wv = threadIdx.x >> 6, lane = threadIdx.x & 63;
    int j = blockIdx.x * 4 + wv;
    int b = j >> 13, n = j & 8191;
    int i0 = idx[j * 3], i1 = idx[j * 3 + 1], i2 = idx[j * 3 + 2];
    float w0 = wgt[j * 3], w1 = wgt[j * 3 + 1], w2 = wgt[j * 3 + 2];
    const u16* r0 = f2t + ((size_t)(b * 2048 + i0)) * 256;
    const u16* r1 = f2t + ((size_t)(b * 2048 + i1)) * 256;
    const u16* r2 = f2t + ((size_t)(b * 2048 + i2)) * 256;
    int c = lane * 4;
    ushort4 v0 = *(const ushort4*)(r0 + c);
    ushort4 v1 = *(const ushort4*)(r1 + c);
    ushort4 v2 = *(const ushort4*)(r2 + c);
    ushort4 o;
    o.x = f2b(w0 * b2f(v0.x) + w1 * b2f(v1.x) + w2 * b2f(v2.x));
    o.y = f2b(w0 * b2f(v0.y) + w1 * b2f(v1.y) + w2 * b2f(v2.y));
    o.z = f2b(w0 * b2f(v0.z) + w1 * b2f(v1.z) + w2 * b2f(v2.z));
    o.w = f2b(w0 * b2f(v0.w) + w1 * b2f(v1.w) + w2 * b2f(v2.w));
    *(ushort4*)(feat + (size_t)j * 384 + c) = o;
    if (lane < 32) {
        int c2 = lane * 4;
        ushort4 f = *(const ushort4*)(f1t + ((size_t)(b * 8192 + n)) * 128 + c2);
        *(ushort4*)(feat + (size_t)j * 384 + 256 + c2) = f;
    }
}

// ---------- GEMM: Y[j][m] = sum_k A[j][k] * Bw[m][k] + bias[m] ----------
// A: [32768][K] bf16 row-major, Bw: [256][K] bf16 row-major, Y: [32768][256] fp32
// block tile 128(j) x 128(m), BK=64, 4 waves each doing 64x64 via 4x4 MFMA 16x16x32
template <int K>
__global__ __launch_bounds__(256, 2) void gemm_kernel(const u16* __restrict__ A,
                                                      const u16* __restrict__ Bw,
                                                      const float* __restrict__ bias,
                                                      float* __restrict__ Y) {
    __shared__ u16 Al[128 * 64];
    __shared__ u16 Bl[128 * 64];
    int tid = threadIdx.x;
    int lane = tid & 63, wv = tid >> 6;
    int j0 = blockIdx.x * 128, m0 = blockIdx.y * 128;
    int l15 = lane & 15, q = lane >> 4;
    int wj = (wv >> 1) * 64, wm = (wv & 1) * 64;
    f32x4 acc[4][4];
#pragma unroll
    for (int i = 0; i < 4; ++i)
#pragma unroll
        for (int jj = 0; jj < 4; ++jj) acc[i][jj] = (f32x4){0.f, 0.f, 0.f, 0.f};

    int rbase = wv * 32;
    int lrow = lane >> 3, lchunk = lane & 7;
    const u16* Ag = A + (size_t)j0 * K;
    const u16* Bg = Bw + (size_t)m0 * K;

    for (int k0 = 0; k0 < K; k0 += 64) {
#pragma unroll
        for (int qq = 0; qq < 4; ++qq) {
            int row = rbase + qq * 8;   // wave-uniform LDS base; HW adds lane*16B
            async_cp16(&Al[row * 64], Ag + (size_t)(row + lrow) * K + k0 + lchunk * 8);
            async_cp16(&Bl[row * 64], Bg + (size_t)(row + lrow) * K + k0 + lchunk * 8);
        }
        __syncthreads();
#pragma unroll
        for (int ks = 0; ks < 2; ++ks) {
            bf16x8 af[4], bfr[4];
#pragma unroll
            for (int i = 0; i < 4; ++i)
                af[i] = *(const bf16x8*)&Al[(wj + i * 16 + l15) * 64 + ks * 32 + q * 8];
#pragma unroll
            for (int i = 0; i < 4; ++i)
                bfr[i] = *(const bf16x8*)&Bl[(wm + i * 16 + l15) * 64 + ks * 32 + q * 8];
#pragma unroll
            for (int i = 0; i < 4; ++i)
#pragma unroll
                for (int jj = 0; jj < 4; ++jj)
                    acc[i][jj] = __builtin_amdgcn_mfma_f32_16x16x32_bf16(af[i], bfr[jj],
                                                                         acc[i][jj], 0, 0, 0);
        }
        __syncthreads();
    }
    // epilogue: D col = lane&15 (channel), row = q*4+reg (j)
#pragma unroll
    for (int jj = 0; jj < 4; ++jj) {
        int m = m0 + wm + jj * 16 + l15;
        float bv = bias[m];
#pragma unroll
        for (int i = 0; i < 4; ++i) {
            int jr = j0 + wj + i * 16 + q * 4;
#pragma unroll
            for (int r = 0; r < 4; ++r)
                Y[(size_t)(jr + r) * 256 + m] = acc[i][jj][r] + bv;
        }
    }
}

// ---------- per-channel sum / sumsq over 32768 rows ----------
__global__ __launch_bounds__(256) void stats_kernel(const float* __restrict__ Y,
                                                    float* __restrict__ sums) {
    int tid = threadIdx.x;
    size_t j0 = (size_t)blockIdx.x * 256;
    float s = 0.f, s2 = 0.f;
    for (int r = 0; r < 256; ++r) {
        float v = Y[(j0 + r) * 256 + tid];
        s += v; s2 += v * v;
    }
    atomicAdd(&sums[tid], s);
    atomicAdd(&sums[256 + tid], s2);
}

// ---------- fold mean/var/gamma/beta into per-channel scale+shift ----------
__global__ void finalize_kernel(float* __restrict__ stats, const float* __restrict__ g,
                                const float* __restrict__ be, int base) {
    int m = threadIdx.x;
    float mean = stats[base + m] * (1.f / 32768.f);
    float var = stats[base + 256 + m] * (1.f / 32768.f) - mean * mean;
    float rs = rsqrtf(var + 1e-5f);
    float aa = g[m] * rs;
    stats[base + 512 + m] = aa;
    stats[base + 768 + m] = be[m] - mean * aa;
}

// ---------- BN+ReLU apply -> bf16 (input of GEMM2) ----------
__global__ __launch_bounds__(256) void apply1_kernel(const float* __restrict__ Y1,
                                                     const float* __restrict__ stats,
                                                     u16* __restrict__ X2) {
    const float* a1 = stats + 512;
    const float* s1 = stats + 768;
    size_t i = ((size_t)blockIdx.x * 256 + threadIdx.x) * 4;
    float4 v = *(const float4*)&Y1[i];
    int m = (int)(i & 255);
    float4 aa = *(const float4*)&a1[m];
    float4 ss = *(const float4*)&s1[m];
    ushort4 o;
    o.x = f2b(fmaxf(v.x * aa.x + ss.x, 0.f));
    o.y = f2b(fmaxf(v.y * aa.y + ss.y, 0.f));
    o.z = f2b(fmaxf(v.z * aa.z + ss.z, 0.f));
    o.w = f2b(fmaxf(v.w * aa.w + ss.w, 0.f));
    *(ushort4*)&X2[i] = o;
}

// ---------- BN2+ReLU + transpose [j][o] -> out[b][o][n] ----------
__global__ __launch_bounds__(256) void final_out_kernel(const float* __restrict__ Y2,
                                                        const float* __restrict__ stats,
                                                        float* __restrict__ out) {
    const float* a2 = stats + 1536;
    const float* s2 = stats + 1792;
    __shared__ float t[64][65];
    int j0 = blockIdx.x * 64, o0 = blockIdx.y * 64;
    int tid = threadIdx.x;
    int c4 = (tid & 15) * 4, rw = tid >> 4;
#pragma unroll
    for (int p = 0; p < 4; ++p) {
        int jl = p * 16 + rw;
        float4 v = *(const float4*)&Y2[(size_t)(j0 + jl) * 256 + o0 + c4];
        t[jl][c4] = v.x; t[jl][c4 + 1] = v.y; t[jl][c4 + 2] = v.z; t[jl][c4 + 3] = v.w;
    }
    __syncthreads();
    int b = j0 >> 13, n0 = j0 & 8191;
#pragma unroll
    for (int p = 0; p < 4; ++p) {
        int ol = p * 16 + rw;
        int o = o0 + ol;
        float a = a2[o], s = s2[o];
        float4 v;
        v.x = fmaxf(t[c4][ol] * a + s, 0.f);
        v.y = fmaxf(t[c4 + 1][ol] * a + s, 0.f);
        v.z = fmaxf(t[c4 + 2][ol] * a + s, 0.f);
        v.w = fmaxf(t[c4 + 3][ol] * a + s, 0.f);
        *(float4*)&out[(size_t)b * 2097152 + (size_t)o * 8192 + n0 + c4] = v;
    }
}

extern "C" void kernel_launch(void* const* d_in, const int* in_sizes, int n_in,
                              void* d_out, int out_size, void* d_ws, size_t ws_size,
                              hipStream_t stream) {
    const float* pos1 = (const float*)d_in[0];
    const float* pos2 = (const float*)d_in[1];
    const float* feature1 = (const float*)d_in[2];
    const float* feature2 = (const float*)d_in[3];
    const float* W1 = (const float*)d_in[4];
    const float* b1 = (const float*)d_in[5];
    const float* g1 = (const float*)d_in[6];
    const float* be1 = (const float*)d_in[7];
    const float* W2 = (const float*)d_in[8];
    const float* b2 = (const float*)d_in[9];
    const float* g2 = (const float*)d_in[10];
    const float* be2 = (const float*)d_in[11];

    char* ws = (char*)d_ws;
    int*   IDX   = (int*)(ws + 0);                 // 393216 B
    float* WGT   = (float*)(ws + 393216);          // 393216 B
    u16*   W1B   = (u16*)(ws + 786432);            // 196608 B
    u16*   W2B   = (u16*)(ws + 983040);            // 131072 B
    float* STATS = (float*)(ws + 1114112);         // 8192 B (sum/sq/a/s x2 layers)
    char*  R0    = ws + 1122304;
    u16*   F2T   = (u16*)(R0);                     // 4 MiB  [B][S][256] bf16
    u16*   F1T   = (u16*)(R0 + 4194304);           // 8 MiB  [B][N][128] bf16
    u16*   FEAT  = (u16*)(R0 + 12582912);          // 24 MiB [32768][384] bf16
    float* Y2    = (float*)(R0);                   // 32 MiB, aliases F2T/F1T/FEAT (dead)
    float* Y1    = (float*)(R0 + 37748736);        // 32 MiB
    u16*   X2    = (u16*)(R0 + 71303168);          // 16 MiB
    float* OUT   = (float*)d_out;

    hipMemsetAsync(STATS, 0, 2048 * sizeof(float), stream);
    cvt_bf16_kernel<<<96, 256, 0, stream>>>(W1, W1B, 24576);
    cvt_bf16_kernel<<<64, 256, 0, stream>>>(W2, W2B, 16384);
    transpose_bf16_kernel<<<dim3(32, 4, 4), 256, 0, stream>>>(feature2, F2T, 256, 2048);
    transpose_bf16_kernel<<<dim3(128, 2, 4), 256, 0, stream>>>(feature1, F1T, 128, 8192);
    three_nn_kernel<<<1024, 256, 0, stream>>>(pos1, pos2, IDX, WGT);
    gather_kernel<<<8192, 256, 0, stream>>>(F2T, F1T, IDX, WGT, FEAT);
    gemm_kernel<384><<<dim3(256, 2), 256, 0, stream>>>(FEAT, W1B, b1, Y1);
    stats_kernel<<<128, 256, 0, stream>>>(Y1, STATS);
    finalize_kernel<<<1, 256, 0, stream>>>(STATS, g1, be1, 0);
    apply1_kernel<<<8192, 256, 0, stream>>>(Y1, STATS, X2);
    gemm_kernel<256><<<dim3(256, 2), 256, 0, stream>>>(X2, W2B, b2, Y2);
    stats_kernel<<<128, 256, 0, stream>>>(Y2, STATS + 1024);
    finalize_kernel<<<1, 256, 0, stream>>>(STATS, g2, be2, 1024);
    final_out_kernel<<<dim3(512, 4), 256, 0, stream>>>(Y2, STATS, OUT);
}

// Round 2
// 218.772 us; speedup vs baseline: 1.1290x; 1.1290x over previous
//
#include <hip/hip_runtime.h>
#include <hip/hip_bf16.h>
#include <cstdint>

typedef unsigned short u16;
typedef __bf16 bf16x8 __attribute__((ext_vector_type(8)));
typedef float f32x4 __attribute__((ext_vector_type(4)));

// ---------- helpers ----------
__device__ __forceinline__ u16 f2b(float f) {          // fp32 -> bf16 RNE
    unsigned int u = __float_as_uint(f);
    u += 0x7fffu + ((u >> 16) & 1u);
    return (u16)(u >> 16);
}
__device__ __forceinline__ float b2f(u16 h) {
    return __uint_as_float(((unsigned int)h) << 16);
}
__device__ __forceinline__ void async_cp16(void* lds, const void* g) {
    __builtin_amdgcn_global_load_lds((const __attribute__((address_space(1))) void*)g,
                                     (__attribute__((address_space(3))) void*)lds, 16, 0, 0);
}

// ---------- fp32 -> bf16 weight conversion (W1 then W2, outputs contiguous) ----------
__global__ __launch_bounds__(256) void cvt_bf16_kernel(const float* __restrict__ w1,
                                                       const float* __restrict__ w2,
                                                       u16* __restrict__ out) {
    int i = blockIdx.x * 256 + threadIdx.x;   // 40960 float4 total (24576 W1 + 16384 W2)
    if (i >= 40960) return;
    const float* src = (i < 24576) ? w1 : w2;
    int k = (i < 24576) ? i : (i - 24576);
    float4 v = *(const float4*)&src[(size_t)k * 4];
    ushort4 o;
    o.x = f2b(v.x); o.y = f2b(v.y); o.z = f2b(v.z); o.w = f2b(v.w);
    *(ushort4*)&out[(size_t)i * 4] = o;
}

// ---------- [B][C][S] fp32 -> [B][S][C] bf16 transpose ----------
__global__ __launch_bounds__(256) void transpose_bf16_kernel(const float* __restrict__ in,
                                                             u16* __restrict__ out,
                                                             int C, int S) {
    __shared__ float t[64][65];
    int s0 = blockIdx.x * 64, c0 = blockIdx.y * 64, b = blockIdx.z;
    const float* ib = in + (size_t)b * C * S;
    u16* ob = out + (size_t)b * S * C;
    int col = threadIdx.x & 63, r0 = threadIdx.x >> 6;
#pragma unroll
    for (int p = 0; p < 16; ++p) {
        int c = p * 4 + r0;
        t[c][col] = ib[(size_t)(c0 + c) * S + s0 + col];
    }
    __syncthreads();
#pragma unroll
    for (int p = 0; p < 16; ++p) {
        int s = p * 4 + r0;
        ob[(size_t)(s0 + s) * C + c0 + col] = f2b(t[col][s]);
    }
}

// ---------- three_nn: top-3 NN + inverse-distance weights ----------
// block = 256 threads = 32 queries x 8 S-chunks of 256; grid = 32768/32 = 1024
// Track top-3 LARGEST t' = dot(p1,p2) - 0.5*|p2|^2  (monotone in -dist).
// dist = |p1|^2 - 2*t'. Branchless cmp/cndmask insert; packed float4 broadcast reads.
__global__ __launch_bounds__(256) void three_nn_kernel(const float* __restrict__ pos1,
                                                       const float* __restrict__ pos2,
                                                       int* __restrict__ idx_out,
                                                       float* __restrict__ w_out) {
    __shared__ float4 pk[2048];        // x, y, z, -0.5*|p|^2
    __shared__ float md[32 * 8 * 3];
    __shared__ int   mi[32 * 8 * 3];
    int tid = threadIdx.x;
    int q = tid & 31, ck = tid >> 5;
    int j = blockIdx.x * 32 + q;
    int b = j >> 13, n = j & 8191;
    const float* p2 = pos2 + (size_t)b * 3 * 2048;
    for (int i = tid; i < 2048; i += 256) {
        float x = p2[i], y = p2[2048 + i], z = p2[4096 + i];
        pk[i] = make_float4(x, y, z, -0.5f * (x * x + y * y + z * z));
    }
    __syncthreads();
    const float* p1 = pos1 + (size_t)b * 3 * 8192;
    float x1 = p1[n], y1 = p1[8192 + n], z1 = p1[16384 + n];
    float n1 = x1 * x1 + y1 * y1 + z1 * z1;

    float g0 = -3.4e38f, g1 = -3.4e38f, g2 = -3.4e38f;
    int i0 = 0, i1 = 0, i2 = 0;
    int sb = ck * 256;
    const float4* pc = pk + sb;
#pragma unroll 4
    for (int it = 0; it < 256; ++it) {
        float4 cd = pc[it];
        int s = sb + it;
        float t = fmaf(x1, cd.x, fmaf(y1, cd.y, fmaf(z1, cd.z, cd.w)));
        bool c0 = t > g0, c1 = t > g1, c2 = t > g2;
        g2 = c1 ? g1 : (c2 ? t : g2);
        i2 = c1 ? i1 : (c2 ? s : i2);
        g1 = c0 ? g0 : (c1 ? t : g1);
        i1 = c0 ? i0 : (c1 ? s : i1);
        g0 = c0 ? t : g0;
        i0 = c0 ? s : i0;
    }
    int base = (q * 8 + ck) * 3;
    md[base] = g0; md[base + 1] = g1; md[base + 2] = g2;
    mi[base] = i0; mi[base + 1] = i1; mi[base + 2] = i2;
    __syncthreads();
    if (tid < 32) {
        float b0 = -3.4e38f, b1 = -3.4e38f, b2 = -3.4e38f;
        int q0 = 0, q1 = 0, q2 = 0;
        for (int c = 0; c < 8; ++c) {           // chunk order => ascending indices => tie keeps lowest
            int bb = (q * 8 + c) * 3;
#pragma unroll
            for (int r = 0; r < 3; ++r) {
                float t = md[bb + r]; int s = mi[bb + r];
                bool c0 = t > b0, c1 = t > b1, c2 = t > b2;
                b2 = c1 ? b1 : (c2 ? t : b2);
                q2 = c1 ? q1 : (c2 ? s : q2);
                b1 = c0 ? b0 : (c1 ? t : b1);
                q1 = c0 ? q0 : (c1 ? s : q1);
                b0 = c0 ? t : b0;
                q0 = c0 ? s : q0;
            }
        }
        float dd0 = fmaxf(fmaf(-2.f, b0, n1), 1e-10f);
        float dd1 = fmaxf(fmaf(-2.f, b1, n1), 1e-10f);
        float dd2 = fmaxf(fmaf(-2.f, b2, n1), 1e-10f);
        float w0 = 1.f / dd0, w1 = 1.f / dd1, w2 = 1.f / dd2;
        float inv = 1.f / (w0 + w1 + w2);
        idx_out[j * 3] = q0; idx_out[j * 3 + 1] = q1; idx_out[j * 3 + 2] = q2;
        w_out[j * 3] = w0 * inv; w_out[j * 3 + 1] = w1 * inv; w_out[j * 3 + 2] = w2 * inv;
    }
}

// ---------- gather + interpolate + concat -> feat [32768][384] bf16 ----------
__global__ __launch_bounds__(256) void gather_kernel(const u16* __restrict__ f2t,
                                                     const u16* __restrict__ f1t,
                                                     const int* __restrict__ idx,
                                                     const float* __restrict__ wgt,
                                                     u16* __restrict__ feat) {
    int wv = threadIdx.x >> 6, lane = threadIdx.x & 63;
    int j = blockIdx.x * 4 + wv;
    int b = j >> 13, n = j & 8191;
    int i0 = idx[j * 3], i1 = idx[j * 3 + 1], i2 = idx[j * 3 + 2];
    float w0 = wgt[j * 3], w1 = wgt[j * 3 + 1], w2 = wgt[j * 3 + 2];
    const u16* r0 = f2t + ((size_t)(b * 2048 + i0)) * 256;
    const u16* r1 = f2t + ((size_t)(b * 2048 + i1)) * 256;
    const u16* r2 = f2t + ((size_t)(b * 2048 + i2)) * 256;
    int c = lane * 4;
    ushort4 v0 = *(const ushort4*)(r0 + c);
    ushort4 v1 = *(const ushort4*)(r1 + c);
    ushort4 v2 = *(const ushort4*)(r2 + c);
    ushort4 o;
    o.x = f2b(w0 * b2f(v0.x) + w1 * b2f(v1.x) + w2 * b2f(v2.x));
    o.y = f2b(w0 * b2f(v0.y) + w1 * b2f(v1.y) + w2 * b2f(v2.y));
    o.z = f2b(w0 * b2f(v0.z) + w1 * b2f(v1.z) + w2 * b2f(v2.z));
    o.w = f2b(w0 * b2f(v0.w) + w1 * b2f(v1.w) + w2 * b2f(v2.w));
    *(ushort4*)(feat + (size_t)j * 384 + c) = o;
    if (lane < 32) {
        int c2 = lane * 4;
        ushort4 f = *(const ushort4*)(f1t + ((size_t)(b * 8192 + n)) * 128 + c2);
        *(ushort4*)(feat + (size_t)j * 384 + 256 + c2) = f;
    }
}

// ---------- GEMM: Yb[j][m] = bf16(sum_k A[j][k]*Bw[m][k] + bias[m]), fused BN stats ----------
template <int K>
__global__ __launch_bounds__(256, 2) void gemm_kernel(const u16* __restrict__ A,
                                                      const u16* __restrict__ Bw,
                                                      const float* __restrict__ bias,
                                                      u16* __restrict__ Yb,
                                                      float* __restrict__ stats) {
    __shared__ u16 Al[128 * 64];
    __shared__ u16 Bl[128 * 64];
    int tid = threadIdx.x;
    int lane = tid & 63, wv = tid >> 6;
    int j0 = blockIdx.x * 128, m0 = blockIdx.y * 128;
    int l15 = lane & 15, q = lane >> 4;
    int wj = (wv >> 1) * 64, wm = (wv & 1) * 64;
    f32x4 acc[4][4];
#pragma unroll
    for (int i = 0; i < 4; ++i)
#pragma unroll
        for (int jj = 0; jj < 4; ++jj) acc[i][jj] = (f32x4){0.f, 0.f, 0.f, 0.f};

    int rbase = wv * 32;
    int lrow = lane >> 3, lchunk = lane & 7;
    const u16* Ag = A + (size_t)j0 * K;
    const u16* Bg = Bw + (size_t)m0 * K;

    for (int k0 = 0; k0 < K; k0 += 64) {
#pragma unroll
        for (int qq = 0; qq < 4; ++qq) {
            int row = rbase + qq * 8;   // wave-uniform LDS base; HW adds lane*16B
            async_cp16(&Al[row * 64], Ag + (size_t)(row + lrow) * K + k0 + lchunk * 8);
            async_cp16(&Bl[row * 64], Bg + (size_t)(row + lrow) * K + k0 + lchunk * 8);
        }
        __syncthreads();
#pragma unroll
        for (int ks = 0; ks < 2; ++ks) {
            bf16x8 af[4], bfr[4];
#pragma unroll
            for (int i = 0; i < 4; ++i)
                af[i] = *(const bf16x8*)&Al[(wj + i * 16 + l15) * 64 + ks * 32 + q * 8];
#pragma unroll
            for (int i = 0; i < 4; ++i)
                bfr[i] = *(const bf16x8*)&Bl[(wm + i * 16 + l15) * 64 + ks * 32 + q * 8];
#pragma unroll
            for (int i = 0; i < 4; ++i)
#pragma unroll
                for (int jj = 0; jj < 4; ++jj)
                    acc[i][jj] = __builtin_amdgcn_mfma_f32_16x16x32_bf16(af[i], bfr[jj],
                                                                         acc[i][jj], 0, 0, 0);
        }
        __syncthreads();
    }
    // epilogue: D col = lane&15 (channel m), row = q*4+reg (j); fused per-channel sum/sumsq
#pragma unroll
    for (int jj = 0; jj < 4; ++jj) {
        int m = m0 + wm + jj * 16 + l15;
        float bv = bias[m];
        float s = 0.f, s2 = 0.f;
#pragma unroll
        for (int i = 0; i < 4; ++i) {
            int jr = j0 + wj + i * 16 + q * 4;
#pragma unroll
            for (int r = 0; r < 4; ++r) {
                float v = acc[i][jj][r] + bv;
                s += v; s2 += v * v;
                Yb[(size_t)(jr + r) * 256 + m] = f2b(v);
            }
        }
        s += __shfl_xor(s, 16); s += __shfl_xor(s, 32);
        s2 += __shfl_xor(s2, 16); s2 += __shfl_xor(s2, 32);
        if (q == 0) {
            atomicAdd(&stats[m], s);
            atomicAdd(&stats[256 + m], s2);
        }
    }
}

// ---------- BN1+ReLU apply (inline finalize) bf16 -> bf16 ----------
__global__ __launch_bounds__(256) void apply1_kernel(const u16* __restrict__ Y1,
                                                     const float* __restrict__ stats,
                                                     const float* __restrict__ g,
                                                     const float* __restrict__ be,
                                                     u16* __restrict__ X2) {
    size_t i = ((size_t)blockIdx.x * 256 + threadIdx.x) * 4;
    int m = (int)(i & 255);
    float4 sm = *(const float4*)&stats[m];
    float4 sq = *(const float4*)&stats[256 + m];
    float4 gg = *(const float4*)&g[m];
    float4 bb = *(const float4*)&be[m];
    const float inv = 1.f / 32768.f;
    float mean, var, aa[4], ss[4];
    mean = sm.x * inv; var = sq.x * inv - mean * mean; aa[0] = gg.x * rsqrtf(var + 1e-5f); ss[0] = bb.x - mean * aa[0];
    mean = sm.y * inv; var = sq.y * inv - mean * mean; aa[1] = gg.y * rsqrtf(var + 1e-5f); ss[1] = bb.y - mean * aa[1];
    mean = sm.z * inv; var = sq.z * inv - mean * mean; aa[2] = gg.z * rsqrtf(var + 1e-5f); ss[2] = bb.z - mean * aa[2];
    mean = sm.w * inv; var = sq.w * inv - mean * mean; aa[3] = gg.w * rsqrtf(var + 1e-5f); ss[3] = bb.w - mean * aa[3];
    ushort4 v = *(const ushort4*)&Y1[i];
    ushort4 o;
    o.x = f2b(fmaxf(b2f(v.x) * aa[0] + ss[0], 0.f));
    o.y = f2b(fmaxf(b2f(v.y) * aa[1] + ss[1], 0.f));
    o.z = f2b(fmaxf(b2f(v.z) * aa[2] + ss[2], 0.f));
    o.w = f2b(fmaxf(b2f(v.w) * aa[3] + ss[3], 0.f));
    *(ushort4*)&X2[i] = o;
}

// ---------- BN2+ReLU (inline finalize) + transpose [j][o] -> out[b][o][n] ----------
__global__ __launch_bounds__(256) void final_out_kernel(const u16* __restrict__ Y2,
                                                        const float* __restrict__ stats,
                                                        const float* __restrict__ g,
                                                        const float* __restrict__ be,
                                                        float* __restrict__ out) {
    __shared__ float t[64][65];
    int j0 = blockIdx.x * 64, o0 = blockIdx.y * 64;
    int tid = threadIdx.x;
    int c4 = (tid & 15) * 4, rw = tid >> 4;
#pragma unroll
    for (int p = 0; p < 4; ++p) {
        int jl = p * 16 + rw;
        ushort4 v = *(const ushort4*)&Y2[(size_t)(j0 + jl) * 256 + o0 + c4];
        t[jl][c4] = b2f(v.x); t[jl][c4 + 1] = b2f(v.y);
        t[jl][c4 + 2] = b2f(v.z); t[jl][c4 + 3] = b2f(v.w);
    }
    __syncthreads();
    int b = j0 >> 13, n0 = j0 & 8191;
    const float inv = 1.f / 32768.f;
#pragma unroll
    for (int p = 0; p < 4; ++p) {
        int ol = p * 16 + rw;
        int o = o0 + ol;
        float mean = stats[o] * inv;
        float var = stats[256 + o] * inv - mean * mean;
        float a = g[o] * rsqrtf(var + 1e-5f);
        float s = be[o] - mean * a;
        float4 v;
        v.x = fmaxf(t[c4][ol] * a + s, 0.f);
        v.y = fmaxf(t[c4 + 1][ol] * a + s, 0.f);
        v.z = fmaxf(t[c4 + 2][ol] * a + s, 0.f);
        v.w = fmaxf(t[c4 + 3][ol] * a + s, 0.f);
        *(float4*)&out[(size_t)b * 2097152 + (size_t)o * 8192 + n0 + c4] = v;
    }
}

extern "C" void kernel_launch(void* const* d_in, const int* in_sizes, int n_in,
                              void* d_out, int out_size, void* d_ws, size_t ws_size,
                              hipStream_t stream) {
    const float* pos1 = (const float*)d_in[0];
    const float* pos2 = (const float*)d_in[1];
    const float* feature1 = (const float*)d_in[2];
    const float* feature2 = (const float*)d_in[3];
    const float* W1 = (const float*)d_in[4];
    const float* b1 = (const float*)d_in[5];
    const float* g1 = (const float*)d_in[6];
    const float* be1 = (const float*)d_in[7];
    const float* W2 = (const float*)d_in[8];
    const float* b2 = (const float*)d_in[9];
    const float* g2 = (const float*)d_in[10];
    const float* be2 = (const float*)d_in[11];

    char* ws = (char*)d_ws;
    int*   IDX   = (int*)(ws + 0);                 // 393216 B
    float* WGT   = (float*)(ws + 393216);          // 393216 B
    u16*   W1B   = (u16*)(ws + 786432);            // 196608 B
    u16*   W2B   = (u16*)(ws + 983040);            // 131072 B (contiguous after W1B)
    float* STATS = (float*)(ws + 1114112);         // 4096 B: sum1/sq1/sum2/sq2
    u16*   F2T   = (u16*)(ws + 1118208);           // 4 MiB  [B][S][256]
    u16*   F1T   = (u16*)(ws + 5312512);           // 8 MiB  [B][N][128]
    u16*   FEAT  = (u16*)(ws + 13701120);          // 24 MiB [32768][384]
    u16*   Y1    = (u16*)(ws + 38866944);          // 16 MiB [32768][256]
    u16*   X2    = (u16*)(ws + 55644160);          // 16 MiB
    u16*   Y2    = (u16*)(ws + 72421376);          // 16 MiB
    float* OUT   = (float*)d_out;

    hipMemsetAsync(STATS, 0, 1024 * sizeof(float), stream);
    cvt_bf16_kernel<<<160, 256, 0, stream>>>(W1, W2, W1B);
    transpose_bf16_kernel<<<dim3(32, 4, 4), 256, 0, stream>>>(feature2, F2T, 256, 2048);
    transpose_bf16_kernel<<<dim3(128, 2, 4), 256, 0, stream>>>(feature1, F1T, 128, 8192);
    three_nn_kernel<<<1024, 256, 0, stream>>>(pos1, pos2, IDX, WGT);
    gather_kernel<<<8192, 256, 0, stream>>>(F2T, F1T, IDX, WGT, FEAT);
    gemm_kernel<384><<<dim3(256, 2), 256, 0, stream>>>(FEAT, W1B, b1, Y1, STATS);
    apply1_kernel<<<8192, 256, 0, stream>>>(Y1, STATS, g1, be1, X2);
    gemm_kernel<256><<<dim3(256, 2), 256, 0, stream>>>(X2, W2B, b2, Y2, STATS + 512);
    final_out_kernel<<<dim3(512, 4), 256, 0, stream>>>(Y2, STATS + 512, g2, be2, OUT);
}